// Round 3
// baseline (2312.874 us; speedup 1.0000x reference)
//
#include <hip/hip_runtime.h>
#include <math.h>

#define H_    8
#define D_    1024
#define S_    1024
#define MID_  2048
#define SOUT_ 512
#define MAXB  24
#define LDP   72   // padded LDS row stride (elements): 144B, 16B-aligned, 2-way bank alias (free)

typedef __bf16 bf16;
typedef __bf16 bf16x8 __attribute__((ext_vector_type(8)));
typedef float  floatx4 __attribute__((ext_vector_type(4)));

struct GemmArgs {
  const void* A[MAXB];
  const void* B[MAXB];
  void*       C[MAXB];
};

// Load 8 consecutive elements as bf16x8, converting if the source is fp32.
template <typename T>
__device__ __forceinline__ bf16x8 load8(const T* p);

template <>
__device__ __forceinline__ bf16x8 load8<float>(const float* p) {
  floatx4 a = *(const floatx4*)p;
  floatx4 b = *(const floatx4*)(p + 4);
  bf16x8 r;
  r[0] = (bf16)a[0]; r[1] = (bf16)a[1]; r[2] = (bf16)a[2]; r[3] = (bf16)a[3];
  r[4] = (bf16)b[0]; r[5] = (bf16)b[1]; r[6] = (bf16)b[2]; r[7] = (bf16)b[3];
  return r;
}
template <>
__device__ __forceinline__ bf16x8 load8<bf16>(const bf16* p) {
  return *(const bf16x8*)p;
}

// C[M x N] = epi( A[M x K] @ B[N x K]^T ), all row-major, K contiguous.
// lda = ldb = K (elements). Tiles: BM=BN=128, BK=64. 256 threads = 4 waves.
// epi: 0 = none, 1 = relu, 2 = tanh. TA/TB may be float (converted to bf16
// during staging) or bf16. TC is float or bf16.
template <typename TA, typename TB, typename TC>
__global__ __launch_bounds__(256, 2)
void gemm_bt_kernel(GemmArgs ga, int K, int ldc, int epi) {
  __shared__ __align__(16) bf16 As[128 * LDP];
  __shared__ __align__(16) bf16 Bs[128 * LDP];

  const TA* __restrict__ A = (const TA*)ga.A[blockIdx.z] + (size_t)blockIdx.y * 128 * K;
  const TB* __restrict__ B = (const TB*)ga.B[blockIdx.z] + (size_t)blockIdx.x * 128 * K;
  TC* __restrict__ C = (TC*)ga.C[blockIdx.z];

  const int t    = threadIdx.x;
  const int lane = t & 63;
  const int wave = t >> 6;
  const int wm   = (wave >> 1) * 64;
  const int wn   = (wave & 1) * 64;
  const int m16  = lane & 15;
  const int quad = lane >> 4;

  floatx4 acc[4][4];
#pragma unroll
  for (int i = 0; i < 4; i++)
#pragma unroll
    for (int j = 0; j < 4; j++) acc[i][j] = (floatx4){0.f, 0.f, 0.f, 0.f};

  for (int k0 = 0; k0 < K; k0 += 64) {
    // Stage A,B tiles: 128 rows x 8 chunks of 8 elements. Thread t, iter i
    // handles linear chunk L = i*256+t -> (row = L>>3, chunk = L&7).
    bf16x8 sa[4], sb[4];
#pragma unroll
    for (int i = 0; i < 4; i++) {
      const int L   = i * 256 + t;
      const int row = L >> 3;
      const int c   = L & 7;
      const size_t goff = (size_t)row * K + k0 + c * 8;
      sa[i] = load8<TA>(A + goff);
      sb[i] = load8<TB>(B + goff);
    }
    __syncthreads();  // previous iteration's LDS reads complete
#pragma unroll
    for (int i = 0; i < 4; i++) {
      const int L   = i * 256 + t;
      const int row = L >> 3;
      const int c   = L & 7;
      *(bf16x8*)&As[row * LDP + c * 8] = sa[i];
      *(bf16x8*)&Bs[row * LDP + c * 8] = sb[i];
    }
    __syncthreads();
#pragma unroll
    for (int ks = 0; ks < 2; ks++) {
      bf16x8 af[4], bfr[4];
#pragma unroll
      for (int f = 0; f < 4; f++) {
        const int ra = wm + f * 16 + m16;
        af[f]  = *(const bf16x8*)&As[ra * LDP + (ks * 4 + quad) * 8];
        const int rb = wn + f * 16 + m16;
        bfr[f] = *(const bf16x8*)&Bs[rb * LDP + (ks * 4 + quad) * 8];
      }
#pragma unroll
      for (int fi = 0; fi < 4; fi++)
#pragma unroll
        for (int fj = 0; fj < 4; fj++)
          acc[fi][fj] = __builtin_amdgcn_mfma_f32_16x16x32_bf16(af[fi], bfr[fj], acc[fi][fj], 0, 0, 0);
    }
  }

  // C/D layout (m89/m91 verified): col = lane&15, row = (lane>>4)*4 + reg
  const size_t cm0 = (size_t)blockIdx.y * 128 + wm + quad * 4;
  const size_t cn0 = (size_t)blockIdx.x * 128 + wn + m16;
#pragma unroll
  for (int fi = 0; fi < 4; fi++)
#pragma unroll
    for (int fj = 0; fj < 4; fj++)
#pragma unroll
      for (int r = 0; r < 4; r++) {
        float v = acc[fi][fj][r];
        if (epi == 1) v = fmaxf(v, 0.f);
        else if (epi == 2) v = tanhf(v);
        C[(cm0 + fi * 16 + r) * (size_t)ldc + cn0 + fj * 16] = (TC)v;
      }
}

// out[C x R] = (bf16) in[R x C]^T   (fp32 -> bf16)
__global__ void transpose_kernel(const float* __restrict__ in, bf16* __restrict__ out,
                                 int R, int Cc) {
  __shared__ bf16 tile[32][33];
  const int bx = blockIdx.x * 32, by = blockIdx.y * 32;
  const int tx = threadIdx.x, ty = threadIdx.y;
#pragma unroll
  for (int i = 0; i < 32; i += 8) tile[ty + i][tx] = (bf16)in[(size_t)(by + ty + i) * Cc + bx + tx];
  __syncthreads();
#pragma unroll
  for (int i = 0; i < 32; i += 8) out[(size_t)(bx + ty + i) * R + by + tx] = tile[tx][ty + i];
}

__global__ void relu_copy_kernel(const float* __restrict__ in, bf16* __restrict__ out, int n) {
  int i = blockIdx.x * 256 + threadIdx.x;
  if (i < n) out[i] = (bf16)fmaxf(in[i], 0.f);
}

// Row d: x[s] = inp[d,s] + yT[s,d]; LN over s (1024).
// transpose_out=1: out[s*1024+d] = ln (h1T);  =0: out[d*1024+s] = relu(ln) (rh2)
__global__ void add_ln_kernel(const float* __restrict__ inp, const bf16* __restrict__ yT,
                              const float* __restrict__ gamma, const float* __restrict__ beta,
                              bf16* __restrict__ out, int transpose_out) {
  const int d = blockIdx.x;
  const int t = threadIdx.x;
  __shared__ float sh1[8], sh2[8];
  float vals[4], sum = 0.f, sq = 0.f;
#pragma unroll
  for (int i = 0; i < 4; i++) {
    const int s = t + i * 256;
    float v = inp[(size_t)d * 1024 + s] + (float)yT[(size_t)s * 1024 + d];
    vals[i] = v; sum += v; sq += v * v;
  }
  for (int off = 32; off > 0; off >>= 1) { sum += __shfl_down(sum, off); sq += __shfl_down(sq, off); }
  const int wave = t >> 6, lane = t & 63;
  if (lane == 0) { sh1[wave] = sum; sh2[wave] = sq; }
  __syncthreads();
  if (t == 0) {
    float s1 = sh1[0] + sh1[1] + sh1[2] + sh1[3];
    float s2 = sh2[0] + sh2[1] + sh2[2] + sh2[3];
    sh1[4] = s1 * (1.f / 1024.f);
    sh2[4] = s2 * (1.f / 1024.f);
  }
  __syncthreads();
  const float mu  = sh1[4];
  const float var = fmaxf(sh2[4] - mu * mu, 0.f);
  const float rs  = rsqrtf(var + 1e-6f);
#pragma unroll
  for (int i = 0; i < 4; i++) {
    const int s = t + i * 256;
    float nv = (vals[i] - mu) * rs * gamma[s] + beta[s];
    if (transpose_out) out[(size_t)s * 1024 + d] = (bf16)nv;
    else               out[(size_t)d * 1024 + s] = (bf16)fmaxf(nv, 0.f);
  }
}

// a32/b32/c32 select operand dtypes (fp32 vs bf16).
static inline void gemm_launch(hipStream_t st, const GemmArgs& ga, int nb,
                               int M, int N, int K, int ldc, int epi,
                               bool a32, bool b32, bool c32) {
  dim3 grid(N / 128, M / 128, nb), blk(256);
  if      ( a32 && !b32 && !c32) gemm_bt_kernel<float, bf16, bf16><<<grid, blk, 0, st>>>(ga, K, ldc, epi);
  else if (!a32 &&  b32 && !c32) gemm_bt_kernel<bf16, float, bf16><<<grid, blk, 0, st>>>(ga, K, ldc, epi);
  else if (!a32 &&  b32 &&  c32) gemm_bt_kernel<bf16, float, float><<<grid, blk, 0, st>>>(ga, K, ldc, epi);
  else                           gemm_bt_kernel<bf16, bf16, bf16><<<grid, blk, 0, st>>>(ga, K, ldc, epi);
}

// One decoder block. qkv{0,1,2} are relu'd bf16 (D x S) activations per q.
// W1/W2/cw1/cw2 are fp32 weights. Writes relu(cat^T) into rcatT (S x H*D),
// then y2 (S x D, bf16) at chunk+2M1.
static void run_block(hipStream_t st, int CH,
                      const bf16* qkv0, const bf16* qkv1p, const bf16* qkv2p,
                      const float* W1, const float* W2,
                      const float* cw1, const float* cw2,
                      bf16* rcatT, bf16* chunk) {
  const size_t M1 = (size_t)1024 * 1024;
  bf16* rz  = chunk;
  bf16* qkT = chunk + (size_t)CH * 6 * M1;
  bf16* vb  = chunk + (size_t)CH * 8 * M1;
  bf16* bT  = chunk + (size_t)CH * 9 * M1;
  const bf16* qkvp[3] = {qkv0, qkv1p, qkv2p};

  for (int h0 = 0; h0 < H_; h0 += CH) {
    GemmArgs ga{};
    // S2: rz[h,q] = relu( qkv[q] @ W1[h,q]^T )   (D x MID), K=S
    for (int b = 0; b < 3 * CH; b++) {
      const int h = h0 + b / 3, q = b % 3;
      ga.A[b] = qkvp[q];
      ga.B[b] = W1 + (size_t)(h * 3 + q) * MID_ * S_;
      ga.C[b] = rz + (size_t)b * D_ * MID_;
    }
    gemm_launch(st, ga, 3 * CH, D_, MID_, S_, MID_, 1, false, true, false);
    // S3a: sT[h,q] = W2[h,q] @ rz[h,q]^T  (S x D) for q=0(q),1(k), K=MID
    for (int b = 0; b < 2 * CH; b++) {
      const int hh = b / 2, q = b % 2;
      ga.A[b] = W2 + (size_t)((h0 + hh) * 3 + q) * S_ * MID_;
      ga.B[b] = rz + (size_t)(hh * 3 + q) * D_ * MID_;
      ga.C[b] = qkT + (size_t)b * S_ * D_;
    }
    gemm_launch(st, ga, 2 * CH, S_, D_, MID_, D_, 0, true, false, false);
    // S3b: v[h] = rz[h,2] @ W2[h,2]^T  (D x S), K=MID
    for (int b = 0; b < CH; b++) {
      ga.A[b] = rz + (size_t)(b * 3 + 2) * D_ * MID_;
      ga.B[b] = W2 + (size_t)((h0 + b) * 3 + 2) * S_ * MID_;
      ga.C[b] = vb + (size_t)b * D_ * S_;
    }
    gemm_launch(st, ga, CH, D_, S_, MID_, S_, 0, false, true, false);
    // S4: bT[h][t,s] = sum_d qT[t,d] kT[s,d]  (S x S), K=D
    for (int b = 0; b < CH; b++) {
      ga.A[b] = qkT + (size_t)(b * 2 + 0) * S_ * D_;
      ga.B[b] = qkT + (size_t)(b * 2 + 1) * S_ * D_;
      ga.C[b] = bT + (size_t)b * S_ * S_;
    }
    gemm_launch(st, ga, CH, S_, S_, D_, S_, 0, false, false, false);
    // S5: attT[h][t,d] = sum_s bT[t,s] v[d,s] -> relu -> rcatT[t, h*D + d]
    for (int b = 0; b < CH; b++) {
      ga.A[b] = bT + (size_t)b * S_ * S_;
      ga.B[b] = vb + (size_t)b * D_ * S_;
      ga.C[b] = rcatT + (size_t)(h0 + b) * D_;
    }
    gemm_launch(st, ga, CH, S_, D_, S_, H_ * D_, 1, false, false, false);
  }
  // S6: ry1 = relu( rcatT @ cw1^T )   (S x MID), K = H*D = 8192
  bf16* ry1 = chunk;
  bf16* y2  = chunk + 2 * M1;
  GemmArgs ga{};
  ga.A[0] = rcatT; ga.B[0] = cw1; ga.C[0] = ry1;
  gemm_launch(st, ga, 1, S_, MID_, H_ * D_, MID_, 1, false, true, false);
  // S7: y2 = ry1 @ cw2^T   (S x D), K=MID   (y2[s,d] = m[d,s])
  ga.A[0] = ry1; ga.B[0] = cw2; ga.C[0] = y2;
  gemm_launch(st, ga, 1, S_, D_, MID_, D_, 0, false, true, false);
}

extern "C" void kernel_launch(void* const* d_in, const int* in_sizes, int n_in,
                              void* d_out, int out_size, void* d_ws, size_t ws_size,
                              hipStream_t stream) {
  (void)in_sizes; (void)n_in; (void)out_size;
  const float* inp    = (const float*)d_in[0];
  const float* enc_k  = (const float*)d_in[1];
  const float* enc_v  = (const float*)d_in[2];
  const float* w_qkv1 = (const float*)d_in[3];
  const float* w_qkv2 = (const float*)d_in[4];
  const float* mh1_W1 = (const float*)d_in[5];
  const float* mh1_W2 = (const float*)d_in[6];
  const float* mh2_W1 = (const float*)d_in[7];
  const float* mh2_W2 = (const float*)d_in[8];
  const float* c1_w1  = (const float*)d_in[9];
  const float* c1_w2  = (const float*)d_in[10];
  const float* c2_w1  = (const float*)d_in[11];
  const float* c2_w2  = (const float*)d_in[12];
  const float* l1_w1  = (const float*)d_in[13];
  const float* l1_w2  = (const float*)d_in[14];
  const float* l2_w1  = (const float*)d_in[15];
  const float* l2_w2  = (const float*)d_in[16];
  const float* gamma  = (const float*)d_in[17];
  const float* beta   = (const float*)d_in[18];
  float* out = (float*)d_out;
  bf16*  ws  = (bf16*)d_ws;

  const size_t M1 = (size_t)1024 * 1024;
  // persistent workspace (all bf16)
  bf16* inpT  = ws;             // 1M
  bf16* rqkv  = ws + 1 * M1;    // 3M   (relu(qkv1); slot 0 reused for relu(q2))
  bf16* rcatT = ws + 4 * M1;    // 8M
  bf16* h1T   = ws + 12 * M1;   // 1M
  bf16* rh2   = ws + 13 * M1;   // 1M
  bf16* renck = ws + 14 * M1;   // 1M
  bf16* rencv = ws + 15 * M1;   // 1M
  bf16* chunk = ws + 16 * M1;   // CH*10M (head-chunk scratch, reused by tail MLP)

  const size_t avail = ws_size / sizeof(bf16);
  int CH = 1;
  if      (16 * M1 + 80 * M1 <= avail) CH = 8;
  else if (16 * M1 + 40 * M1 <= avail) CH = 4;
  else if (16 * M1 + 20 * M1 <= avail) CH = 2;

  // inpT = (bf16) inp^T  (S x D)
  transpose_kernel<<<dim3(S_ / 32, D_ / 32), dim3(32, 8), 0, stream>>>(inp, inpT, D_, S_);

  // S1: rqkv = relu( w_qkv1(3D x D) @ inp ) via B = inpT, M=3D
  {
    GemmArgs ga{};
    ga.A[0] = w_qkv1; ga.B[0] = inpT; ga.C[0] = rqkv;
    gemm_launch(stream, ga, 1, 3 * D_, S_, D_, S_, 1, true, false, false);
  }

  // ---- decoder block 1 ----
  run_block(stream, CH, rqkv, rqkv + M1, rqkv + 2 * M1, mh1_W1, mh1_W2, c1_w1, c1_w2, rcatT, chunk);
  bf16* y2 = chunk + 2 * M1;
  add_ln_kernel<<<dim3(D_), dim3(256), 0, stream>>>(inp, y2, gamma, beta, h1T, 1);

  // relu(enc_k), relu(enc_v) -> bf16
  relu_copy_kernel<<<dim3(4096), dim3(256), 0, stream>>>(enc_k, renck, (int)M1);
  relu_copy_kernel<<<dim3(4096), dim3(256), 0, stream>>>(enc_v, rencv, (int)M1);

  // q2 = relu( w_qkv2[0] @ h1 ) via B = h1T
  {
    GemmArgs ga{};
    ga.A[0] = w_qkv2; ga.B[0] = h1T; ga.C[0] = rqkv;
    gemm_launch(stream, ga, 1, D_, S_, D_, S_, 1, true, false, false);
  }

  // ---- decoder block 2 ----
  run_block(stream, CH, rqkv, renck, rencv, mh2_W1, mh2_W2, c2_w1, c2_w2, rcatT, chunk);
  add_ln_kernel<<<dim3(D_), dim3(256), 0, stream>>>(inp, y2, gamma, beta, rh2, 0);

  // ---- final MLP: rh2 (D x S, relu'd bf16) -> out (D x SOUT fp32) ----
  bf16* rx1 = chunk;            // D x MID
  bf16* rx2 = chunk + 2 * M1;   // D x SOUT
  bf16* ryf = chunk + 3 * M1;   // D x MID
  {
    GemmArgs ga{};
    ga.A[0] = rh2; ga.B[0] = l1_w1; ga.C[0] = rx1;
    gemm_launch(stream, ga, 1, D_, MID_, S_, MID_, 1, false, true, false);
    ga.A[0] = rx1; ga.B[0] = l1_w2; ga.C[0] = rx2;
    gemm_launch(stream, ga, 1, D_, SOUT_, MID_, SOUT_, 1, false, true, false);
    ga.A[0] = rx2; ga.B[0] = l2_w1; ga.C[0] = ryf;
    gemm_launch(stream, ga, 1, D_, MID_, SOUT_, MID_, 1, false, true, false);
    ga.A[0] = ryf; ga.B[0] = l2_w2; ga.C[0] = out;
    gemm_launch(stream, ga, 1, D_, SOUT_, MID_, SOUT_, 2, false, true, true);
  }
}